// Round 8
// baseline (4822.500 us; speedup 1.0000x reference)
//
#include <hip/hip_runtime.h>

// GLA (gated linear attention) forward scan, fp32.
// q,k,v,g: [B=2, H=16, T=4096, D=128] fp32.  out = (o [B,H,T,D], h_final [B,H,D,D]).
//
// R5: lane owns full column h[128] -> 212 unified regs -> AGPR round-trips,
//     2 waves/SIMD, k4=730us @ VALUBusy 20%.
// R6: h[64]/lane + __launch_bounds__(256,4) cap=128 -> allocator demoted the
//     state (VGPR_Count=48!) -> scratch/AGPR chain latency, k4=1400us. REVERTED.
// R7: h[32]/lane (4 lanes per state column), 512-thread blocks,
//     __launch_bounds__(512,4): ~70 regs needed << 128 cap -> state stays in
//     real VGPRs AND 4 waves/SIMD. Two shfl_xor per step for the q.h reduce.
//
// Structure (unchanged): segmented scan over T, S=32 segments of 128 steps.
//   k1: eg = exp(g), A = exp(segment-sum g)
//   k2: per-segment contribution C_seg (scan from 0)
//   k3: sequential combine -> per-seg initial states + h_final
//   k4: re-scan from true initial state, emit o

#define BHN 32
#define TT 4096
#define DDIM 128
#define NSEG 32
#define TSEG 128   // TT / NSEG
#define LSPLIT 4   // lanes per state column
#define HK 32      // per-lane kappa slice (DDIM / LSPLIT)
#define GLA_SCALE 0.08838834764831845f  // 1/sqrt(128)

__device__ __forceinline__ float4 ldu4(const float* p) {
  return *reinterpret_cast<const float4*>(p);
}

// ---- k1: eg = exp(g); A[bh,seg,kk] = exp(sum_t g) ----
__global__ void k1_gate(const float* __restrict__ g, float* __restrict__ eg,
                        float* __restrict__ A) {
  const int bh = blockIdx.x / NSEG;
  const int seg = blockIdx.x % NSEG;
  const int kk = threadIdx.x;  // 0..127 (key index)
  const size_t base = ((size_t)bh * TT + (size_t)seg * TSEG) * DDIM + kk;
  const float* gp = g + base;
  float* ep = eg + base;
  float sum = 0.f;
#pragma unroll 4
  for (int t = 0; t < TSEG; ++t) {
    float gv = gp[(size_t)t * DDIM];
    sum += gv;
    ep[(size_t)t * DDIM] = expf(gv);
  }
  A[((size_t)bh * NSEG + seg) * DDIM + kk] = expf(sum);
}

// ---- k2: per-segment state contribution (scan from zero, no output) ----
// 512 threads: sub = tid&3 (kappa quarter), nu = tid>>2 (value column).
__global__ __launch_bounds__(512, 4) void k2_contrib(
    const float* __restrict__ kten, const float* __restrict__ vten,
    const float* __restrict__ eg, float* __restrict__ hC) {
  const int bh = blockIdx.x / NSEG;
  const int seg = blockIdx.x % NSEG;
  const int sub = threadIdx.x & (LSPLIT - 1);
  const int nu = threadIdx.x >> 2;
  const int ko = sub * HK;  // first kappa this lane owns
  float h[HK];
#pragma unroll
  for (int i = 0; i < HK; ++i) h[i] = 0.f;
  const size_t base = ((size_t)bh * TT + (size_t)seg * TSEG) * DDIM;
  for (int t = 0; t < TSEG; ++t) {
    const float* ep = eg + base + (size_t)t * DDIM + ko;
    const float* kp = kten + base + (size_t)t * DDIM + ko;
    const float vv = vten[base + (size_t)t * DDIM + nu];
#pragma unroll
    for (int c = 0; c < HK / 4; ++c) {
      float4 e4 = ldu4(ep + 4 * c);
      float4 k4 = ldu4(kp + 4 * c);
      h[4 * c + 0] = fmaf(h[4 * c + 0], e4.x, k4.x * vv);
      h[4 * c + 1] = fmaf(h[4 * c + 1], e4.y, k4.y * vv);
      h[4 * c + 2] = fmaf(h[4 * c + 2], e4.z, k4.z * vv);
      h[4 * c + 3] = fmaf(h[4 * c + 3], e4.w, k4.w * vv);
    }
  }
  // write C[bh,seg,kappa,nu]
  float* out = hC + ((size_t)bh * NSEG + seg) * (DDIM * DDIM) +
               (size_t)ko * DDIM + nu;
#pragma unroll
  for (int i = 0; i < HK; ++i) out[(size_t)i * DDIM] = h[i];
}

// ---- k3: combine segments sequentially (in place: C[s] -> h_init[s]) ----
__global__ void k3_combine(float* __restrict__ hC, const float* __restrict__ A,
                           float* __restrict__ hfinal) {
  const size_t idx = (size_t)blockIdx.x * 256 + threadIdx.x;  // over BH*D*D
  const int bh = (int)(idx >> 14);
  const int kk = (int)((idx >> 7) & 127);
  const size_t knu = idx & 16383;  // (kappa,nu) within a state
  float h = 0.f;
  for (int s = 0; s < NSEG; ++s) {
    const size_t off = ((size_t)bh * NSEG + s) * 16384 + knu;
    const float c = hC[off];
    hC[off] = h;  // initial state for segment s
    h = fmaf(h, A[((size_t)bh * NSEG + s) * DDIM + kk], c);
  }
  hfinal[(size_t)bh * 16384 + knu] = h;
}

// ---- k4: re-scan each segment from its true initial state, emit o ----
__global__ __launch_bounds__(512, 4) void k4_out(
    const float* __restrict__ qten, const float* __restrict__ kten,
    const float* __restrict__ vten, const float* __restrict__ eg,
    const float* __restrict__ h0, float* __restrict__ o) {
  const int bh = blockIdx.x / NSEG;
  const int seg = blockIdx.x % NSEG;
  const int sub = threadIdx.x & (LSPLIT - 1);
  const int nu = threadIdx.x >> 2;
  const int ko = sub * HK;
  float h[HK];
  const float* hi = h0 + ((size_t)bh * NSEG + seg) * (DDIM * DDIM) +
                    (size_t)ko * DDIM + nu;
#pragma unroll
  for (int i = 0; i < HK; ++i) h[i] = hi[(size_t)i * DDIM];
  const size_t base = ((size_t)bh * TT + (size_t)seg * TSEG) * DDIM;
  for (int t = 0; t < TSEG; ++t) {
    const float* ep = eg + base + (size_t)t * DDIM + ko;
    const float* kp = kten + base + (size_t)t * DDIM + ko;
    const float* qp = qten + base + (size_t)t * DDIM + ko;
    const float vv = vten[base + (size_t)t * DDIM + nu];
    float a0 = 0.f, a1 = 0.f, a2 = 0.f, a3 = 0.f;  // 4 acc chains for ILP
#pragma unroll
    for (int c = 0; c < HK / 4; ++c) {
      float4 e4 = ldu4(ep + 4 * c);
      float4 k4 = ldu4(kp + 4 * c);
      float4 q4 = ldu4(qp + 4 * c);
      float t0 = fmaf(h[4 * c + 0], e4.x, k4.x * vv);
      h[4 * c + 0] = t0;
      a0 = fmaf(q4.x, t0, a0);
      float t1 = fmaf(h[4 * c + 1], e4.y, k4.y * vv);
      h[4 * c + 1] = t1;
      a1 = fmaf(q4.y, t1, a1);
      float t2 = fmaf(h[4 * c + 2], e4.z, k4.z * vv);
      h[4 * c + 2] = t2;
      a2 = fmaf(q4.z, t2, a2);
      float t3 = fmaf(h[4 * c + 3], e4.w, k4.w * vv);
      h[4 * c + 3] = t3;
      a3 = fmaf(q4.w, t3, a3);
    }
    float part = ((a0 + a1) + (a2 + a3));
    part += __shfl_xor(part, 1);  // combine kappa quarters (lanes ^1, ^2)
    part += __shfl_xor(part, 2);
    if (sub == 0) o[base + (size_t)t * DDIM + nu] = part * GLA_SCALE;
  }
}

extern "C" void kernel_launch(void* const* d_in, const int* in_sizes, int n_in,
                              void* d_out, int out_size, void* d_ws,
                              size_t ws_size, hipStream_t stream) {
  const float* q = (const float*)d_in[0];
  const float* k = (const float*)d_in[1];
  const float* v = (const float*)d_in[2];
  const float* g = (const float*)d_in[3];

  float* o = (float*)d_out;                      // [BH, T, D]
  float* hfinal = o + (size_t)BHN * TT * DDIM;   // [BH, D, D]

  // workspace layout (fp32): eg[BH*T*D] | C/h_init[BH*NSEG*D*D] | A[BH*NSEG*D]
  float* ws = (float*)d_ws;
  float* eg = ws;
  float* hC = ws + (size_t)BHN * TT * DDIM;
  float* A = hC + (size_t)BHN * NSEG * DDIM * DDIM;

  k1_gate<<<BHN * NSEG, 128, 0, stream>>>(g, eg, A);
  k2_contrib<<<BHN * NSEG, 512, 0, stream>>>(k, v, eg, hC);
  k3_combine<<<(BHN * DDIM * DDIM) / 256, 256, 0, stream>>>(hC, A, hfinal);
  k4_out<<<BHN * NSEG, 512, 0, stream>>>(q, k, v, eg, hC, o);
}

// Round 11
// 366.851 us; speedup vs baseline: 13.1457x; 13.1457x over previous
//
#include <hip/hip_runtime.h>

// GLA forward, CHUNKED formulation (R10 rewrite).
// q,k,v,g: [B=2,H=16,T=4096,D=128] fp32. out = (o [BH,T,D], h_final [BH,D,D]).
//
// Why: R5-R8 proved the VALU scan is structurally allocator-hostile: the
// 128x128 fp32 state never stays in arch VGPRs (AGPR/scratch demotion every
// time), and its floor is ~10.7e12 VALU FLOPs anyway. Chunked form puts the
// state in MFMA ACCUMULATORS (cannot be demoted) and does the heavy math as
// fp16 MFMA with fp32 accumulation.
//
// Math per (bh): chunks of 16 steps. G = inclusive cumsum(g) in chunk,
// Gc = chunk total. Entering state H0:
//   o_i   = [q_i e^{G_i}] . H0   +  sum_{j<=i} (q_i.k_j e^{G_i-G_j}) v_j
//   Hend  = diag(e^{Gc}) H0 + sum_j [k_j e^{Gc-G_j}] v_j^T
// Intra S_ij = dot(QUR_i, KW_j): QUR = q e^{G} e^{min(-Gc,69)}, KW = k e^{Gc-G}
// (both fp32-safe; clamp unreachable in practice). S,qtil,ktil,v -> fp16 for MFMA.
// 3-phase across 32 segments of 128: kA = per-seg local o + seg-final state C
// + seg decay D + qseg(=q e^{G^seg}, fp16); kB = old (verified) k3 combine;
// kC: o += SCALE * qseg . H0_seg (GEMM).

#define BHN 32
#define TT 4096
#define DDIM 128
#define NSEG 32
#define TSEG 128
#define NCH 8          // chunks per segment
#define CH 16          // chunk length
#define GLA_SCALE 0.08838834764831845f

typedef _Float16 f16;
typedef f16 f16x4 __attribute__((ext_vector_type(4)));
typedef float f32x4v __attribute__((ext_vector_type(4)));

#define MFMA16(a, b, c) __builtin_amdgcn_mfma_f32_16x16x16f16((a), (b), (c), 0, 0, 0)

__device__ __forceinline__ float4 ldu4(const float* p) {
  return *reinterpret_cast<const float4*>(p);
}

// ---------------- kA: per-(bh,seg) chunked scan ----------------
// block 512 = 8 waves; wave w owns state tile-row w: tiles (w,c) c=0..7,
// Hacc[c][j] = H[dk = w*16 + (lane>>4)*4 + j][dv = c*16 + (lane&15)].
__global__ void __launch_bounds__(512) kA(
    const float* __restrict__ q, const float* __restrict__ kt,
    const float* __restrict__ vt, const float* __restrict__ g,
    float* __restrict__ o, f16* __restrict__ qs, float* __restrict__ hC,
    float* __restrict__ Dsg) {
  __shared__ float sgqur[16][132];  // g during cumsum, then QUR (fp32)
  __shared__ float sG[16][132];     // inclusive cumsum
  __shared__ float sKW[16][132];    // k * e^{Gc-G} (fp32, for diag dots)
  __shared__ f16 sQ[16][132];       // qtil = q e^G (fp16, o-GEMM A)
  __shared__ f16 sKT[128][20];      // ktil^T [d][t] (fp16, update A)
  __shared__ f16 sV[16][136];       // v (fp16, B operand)
  __shared__ f16 sS[16][20];        // diag S (fp16)
  __shared__ f16 sH[128][136];      // H snapshot (fp16, o-GEMM B)
  __shared__ float sEgc[128];       // e^{Gc}
  __shared__ float sSeg[128];       // running product of prior chunks' e^{Gc}

  const int bh = blockIdx.x >> 5;
  const int seg = blockIdx.x & 31;
  const int tid = threadIdx.x;
  const int lane = tid & 63;
  const int wv = tid >> 6;
  const int lrow = lane & 15;
  const int lgrp = lane >> 4;
  const int tld = tid >> 5;        // load row 0..15
  const int dld = (tid & 31) * 4;  // load col (float4)

  f32x4v Hacc[8];
#pragma unroll
  for (int c = 0; c < 8; ++c) Hacc[c] = (f32x4v){0.f, 0.f, 0.f, 0.f};
  if (tid < 128) sSeg[tid] = 1.f;

  for (int ch = 0; ch < NCH; ++ch) {
    const size_t rbase = (size_t)bh * TT + seg * TSEG + ch * CH;
    // ---- P1: load q,k,v,g (regs), g -> LDS ----
    const size_t goff = (rbase + tld) * DDIM + dld;
    float4 q4 = ldu4(q + goff);
    float4 k4 = ldu4(kt + goff);
    float4 v4 = ldu4(vt + goff);
    float4 g4 = ldu4(g + goff);
    sgqur[tld][dld + 0] = g4.x;
    sgqur[tld][dld + 1] = g4.y;
    sgqur[tld][dld + 2] = g4.z;
    sgqur[tld][dld + 3] = g4.w;
    __syncthreads();
    // ---- cumsum over 16 steps, one thread per dim ----
    if (tid < 128) {
      float a = 0.f;
#pragma unroll
      for (int t = 0; t < CH; ++t) {
        a += sgqur[t][tid];
        sG[t][tid] = a;
      }
    }
    __syncthreads();
    // ---- derive scaled operands ----
    {
      const float qv[4] = {q4.x, q4.y, q4.z, q4.w};
      const float kv[4] = {k4.x, k4.y, k4.z, k4.w};
      const float vv[4] = {v4.x, v4.y, v4.z, v4.w};
#pragma unroll
      for (int i = 0; i < 4; ++i) {
        const int d = dld + i;
        const float G = sG[tld][d];
        const float Gc = sG[15][d];
        const float u = expf(G);
        const float w = expf(Gc - G);
        const float rr = expf(fminf(-Gc, 69.f));
        const float qu = qv[i] * u;
        const float kw = kv[i] * w;
        sgqur[tld][d] = qu * rr;  // QUR (overwrites g after barrier)
        sKW[tld][d] = kw;
        sQ[tld][d] = (f16)qu;
        sKT[d][tld] = (f16)kw;
        sV[tld][d] = (f16)vv[i];
        qs[(rbase + tld) * DDIM + d] = (f16)(qu * sSeg[d]);
        if (tld == 15) sEgc[d] = expf(Gc);
      }
    }
    __syncthreads();
    // ---- P2: diagonal causal S (fp32 dots) ||  P3a: snapshot H -> f16 ----
    if (tid < 256) {
      const int si = tid >> 4, sj = tid & 15;
      float s = 0.f;
      if (sj <= si) {
#pragma unroll
        for (int dd = 0; dd < DDIM; dd += 4) {
          const float4 a = *reinterpret_cast<const float4*>(&sgqur[si][dd]);
          const float4 b = *reinterpret_cast<const float4*>(&sKW[sj][dd]);
          s = fmaf(a.x, b.x, s);
          s = fmaf(a.y, b.y, s);
          s = fmaf(a.z, b.z, s);
          s = fmaf(a.w, b.w, s);
        }
      }
      sS[si][sj] = (f16)s;
    }
#pragma unroll
    for (int c = 0; c < 8; ++c) {
#pragma unroll
      for (int j = 0; j < 4; ++j)
        sH[wv * 16 + lgrp * 4 + j][c * 16 + lrow] = (f16)Hacc[c][j];
    }
    __syncthreads();
    // ---- P3b: o tile (rows t, cols dv-block wv) ----
    {
      f32x4v oacc = (f32x4v){0.f, 0.f, 0.f, 0.f};
#pragma unroll
      for (int r = 0; r < 8; ++r) {
        f16x4 a = *reinterpret_cast<const f16x4*>(&sQ[lrow][r * 16 + lgrp * 4]);
        f16x4 b;
        b[0] = sH[r * 16 + lgrp * 4 + 0][wv * 16 + lrow];
        b[1] = sH[r * 16 + lgrp * 4 + 1][wv * 16 + lrow];
        b[2] = sH[r * 16 + lgrp * 4 + 2][wv * 16 + lrow];
        b[3] = sH[r * 16 + lgrp * 4 + 3][wv * 16 + lrow];
        oacc = MFMA16(a, b, oacc);
      }
      {
        f16x4 a = *reinterpret_cast<const f16x4*>(&sS[lrow][lgrp * 4]);
        f16x4 b;
        b[0] = sV[lgrp * 4 + 0][wv * 16 + lrow];
        b[1] = sV[lgrp * 4 + 1][wv * 16 + lrow];
        b[2] = sV[lgrp * 4 + 2][wv * 16 + lrow];
        b[3] = sV[lgrp * 4 + 3][wv * 16 + lrow];
        oacc = MFMA16(a, b, oacc);
      }
#pragma unroll
      for (int j = 0; j < 4; ++j)
        o[(rbase + lgrp * 4 + j) * DDIM + wv * 16 + lrow] = oacc[j] * GLA_SCALE;
    }
    // ---- P4: state update H = diag(e^Gc) H + ktil^T v ----
    {
      float ee[4];
#pragma unroll
      for (int j = 0; j < 4; ++j) ee[j] = sEgc[wv * 16 + lgrp * 4 + j];
#pragma unroll
      for (int c = 0; c < 8; ++c) {
        f16x4 a =
            *reinterpret_cast<const f16x4*>(&sKT[wv * 16 + lrow][lgrp * 4]);
        f16x4 b;
        b[0] = sV[lgrp * 4 + 0][c * 16 + lrow];
        b[1] = sV[lgrp * 4 + 1][c * 16 + lrow];
        b[2] = sV[lgrp * 4 + 2][c * 16 + lrow];
        b[3] = sV[lgrp * 4 + 3][c * 16 + lrow];
#pragma unroll
        for (int j = 0; j < 4; ++j) Hacc[c][j] *= ee[j];
        Hacc[c] = MFMA16(a, b, Hacc[c]);
      }
    }
    __syncthreads();
    if (tid < 128) sSeg[tid] *= sEgc[tid];
    // next chunk's barriers order sSeg before its readers
  }
  __syncthreads();
  // ---- epilogue: segment-final state + decay ----
  float* hout = hC + (size_t)(bh * NSEG + seg) * (DDIM * DDIM);
#pragma unroll
  for (int c = 0; c < 8; ++c) {
#pragma unroll
    for (int j = 0; j < 4; ++j)
      hout[(size_t)(wv * 16 + lgrp * 4 + j) * DDIM + c * 16 + lrow] =
          Hacc[c][j];
  }
  if (tid < 128) Dsg[(size_t)(bh * NSEG + seg) * DDIM + tid] = sSeg[tid];
}

// ---------------- kB: sequential combine (VERBATIM passing k3) ----------------
__global__ void k3_combine(float* __restrict__ hC, const float* __restrict__ A,
                           float* __restrict__ hfinal) {
  const size_t idx = (size_t)blockIdx.x * 256 + threadIdx.x;
  const int bh = (int)(idx >> 14);
  const int kk = (int)((idx >> 7) & 127);
  const size_t knu = idx & 16383;
  float h = 0.f;
  for (int s = 0; s < NSEG; ++s) {
    const size_t off = ((size_t)bh * NSEG + s) * 16384 + knu;
    const float c = hC[off];
    hC[off] = h;
    h = fmaf(h, A[((size_t)bh * NSEG + s) * DDIM + kk], c);
  }
  hfinal[(size_t)bh * 16384 + knu] = h;
}

// ---------------- kC: o += SCALE * qseg . H0_seg ----------------
__global__ void __launch_bounds__(512) kC(const f16* __restrict__ qs,
                                          const float* __restrict__ hC,
                                          float* __restrict__ o) {
  __shared__ f16 sH[128][136];
  __shared__ f16 sQs[128][132];
  const int bh = blockIdx.x >> 5;
  const int seg = blockIdx.x & 31;
  const int tid = threadIdx.x;
  const int lane = tid & 63;
  const int wv = tid >> 6;
  const int lrow = lane & 15;
  const int lgrp = lane >> 4;
  const size_t hoff = (size_t)(bh * NSEG + seg) * (DDIM * DDIM);
  const size_t qoff = ((size_t)bh * TT + seg * TSEG) * DDIM;
  for (int e = tid; e < DDIM * DDIM; e += 512) {
    sH[e >> 7][e & 127] = (f16)hC[hoff + e];
    sQs[e >> 7][e & 127] = qs[qoff + e];
  }
  __syncthreads();
#pragma unroll
  for (int c = 0; c < 8; ++c) {
    f32x4v acc = (f32x4v){0.f, 0.f, 0.f, 0.f};
#pragma unroll
    for (int r = 0; r < 8; ++r) {
      f16x4 a =
          *reinterpret_cast<const f16x4*>(&sQs[wv * 16 + lrow][r * 16 + lgrp * 4]);
      f16x4 b;
      b[0] = sH[r * 16 + lgrp * 4 + 0][c * 16 + lrow];
      b[1] = sH[r * 16 + lgrp * 4 + 1][c * 16 + lrow];
      b[2] = sH[r * 16 + lgrp * 4 + 2][c * 16 + lrow];
      b[3] = sH[r * 16 + lgrp * 4 + 3][c * 16 + lrow];
      acc = MFMA16(a, b, acc);
    }
#pragma unroll
    for (int j = 0; j < 4; ++j) {
      const size_t adr =
          ((size_t)bh * TT + seg * TSEG + wv * 16 + lgrp * 4 + j) * DDIM +
          c * 16 + lrow;
      o[adr] += GLA_SCALE * acc[j];
    }
  }
}

extern "C" void kernel_launch(void* const* d_in, const int* in_sizes, int n_in,
                              void* d_out, int out_size, void* d_ws,
                              size_t ws_size, hipStream_t stream) {
  const float* q = (const float*)d_in[0];
  const float* k = (const float*)d_in[1];
  const float* v = (const float*)d_in[2];
  const float* g = (const float*)d_in[3];

  float* o = (float*)d_out;                     // [BH,T,D]
  float* hfinal = o + (size_t)BHN * TT * DDIM;  // [BH,D,D]

  // ws: qs f16 [BH*T*D] (33.5MB) | hC f32 [BH*NSEG*D*D] (67MB) | D f32 (0.5MB)
  f16* qs = (f16*)d_ws;
  float* hC = (float*)((char*)d_ws + (size_t)BHN * TT * DDIM * 2);
  float* Dsg = hC + (size_t)BHN * NSEG * DDIM * DDIM;

  kA<<<BHN * NSEG, 512, 0, stream>>>(q, k, v, g, o, qs, hC, Dsg);
  k3_combine<<<(BHN * DDIM * DDIM) / 256, 256, 0, stream>>>(hC, Dsg, hfinal);
  kC<<<BHN * NSEG, 512, 0, stream>>>(qs, hC, o);
}